// Round 8
// baseline (327.720 us; speedup 1.0000x reference)
//
#include <hip/hip_runtime.h>

typedef unsigned short u16;
typedef __bf16 bf16x8 __attribute__((ext_vector_type(8)));
typedef float f32x4 __attribute__((ext_vector_type(4)));
typedef _Float16 f16x4 __attribute__((ext_vector_type(4)));
typedef unsigned short u16x8 __attribute__((ext_vector_type(8)));
typedef unsigned short u16x4 __attribute__((ext_vector_type(4)));

__device__ __forceinline__ u16 f2bf(float x) {
  union { float f; unsigned u; } c; c.f = x;
  unsigned r = c.u + 0x7FFFu + ((c.u >> 16) & 1u);
  return (u16)(r >> 16);
}

__device__ __forceinline__ void glds16(const void* g, void* s) {
  __builtin_amdgcn_global_load_lds(
      (const __attribute__((address_space(1))) unsigned int*)g,
      (__attribute__((address_space(3))) unsigned int*)s, 16, 0, 0);
}

// ---- fused preprocessing: cast x -> bf16; transpose+cast both weight matrices ----
__global__ __launch_bounds__(256) void k_pre(const float* __restrict__ x,
                                             u16* __restrict__ xbf,
                                             const float* __restrict__ wq,
                                             u16* __restrict__ wqt,
                                             const float* __restrict__ wp,
                                             u16* __restrict__ wpt) {
  __shared__ float tile[64 * 68];
  int bx = blockIdx.x;
  int tid = threadIdx.x;
  if (bx < 3072) {  // cast x
    int i = bx * 256 + tid;
    const f32x4* xp = (const f32x4*)x + (size_t)i * 2;
    f32x4 a = xp[0], b = xp[1];
    u16x8 r;
    r[0] = f2bf(a[0]); r[1] = f2bf(a[1]); r[2] = f2bf(a[2]); r[3] = f2bf(a[3]);
    r[4] = f2bf(b[0]); r[5] = f2bf(b[1]); r[6] = f2bf(b[2]); r[7] = f2bf(b[3]);
    *((u16x8*)xbf + i) = r;
    return;
  }
  const float* src; u16* dst; int Nn, n0, k0;
  const int K = 768;
  if (bx < 3504) { int b2 = bx - 3072; src = wq; dst = wqt; Nn = 2304;
                   n0 = (b2 % 36) * 64; k0 = (b2 / 36) * 64; }
  else           { int b2 = bx - 3504; src = wp; dst = wpt; Nn = 768;
                   n0 = (b2 % 12) * 64; k0 = (b2 / 12) * 64; }
  int rr = tid >> 4, cc = tid & 15;
#pragma unroll
  for (int r = 0; r < 4; ++r) {
    int k = r * 16 + rr;
    f32x4 v = *(const f32x4*)(src + (size_t)(k0 + k) * Nn + n0 + cc * 4);
    *(f32x4*)(tile + k * 68 + cc * 4) = v;
  }
  __syncthreads();
#pragma unroll
  for (int r = 0; r < 4; ++r) {
    int n = r * 16 + rr;
    u16x4 o;
#pragma unroll
    for (int j = 0; j < 4; ++j) o[j] = f2bf(tile[(cc * 4 + j) * 68 + n]);
    *(u16x4*)(dst + (size_t)(n0 + n) * K + k0 + cc * 4) = o;
  }
}

// ------------- BMx128 bf16 GEMM, BK=32 double-buffered vmcnt pipeline -------------
// PROJ=false: Q/K cols -> bf16 qkv (Q scaled by SCALE*log2e); V cols -> vt
// transposed AND chunk4-permuted within each seq-128 tile (see k_attn PV layout).
template <int BM, int N, bool PROJ>
__global__ __launch_bounds__(256, 4) void k_gemm(const u16* __restrict__ A,
                                                 const u16* __restrict__ Bt,
                                                 u16* __restrict__ Co,
                                                 float* __restrict__ Cf,
                                                 const float* __restrict__ bias,
                                                 u16* __restrict__ vt) {
  const int K = 768;
  const int FI = BM / 32;
  __shared__ u16 lds[2 * (BM + 128) * 32];  // dbuf: A tile BM x32 + B tile 128x32
  const int tid = threadIdx.x;
  const int wave = tid >> 6, lane = tid & 63;
  const int lr = lane & 15, lq = lane >> 4;
  const int m0 = blockIdx.x * BM, n0 = blockIdx.y * 128;
  const int wr = (wave >> 1) * (BM / 2), wc = (wave & 1) * 64;
  f32x4 acc[FI][4] = {};

  auto stage = [&](int t, int buf) {
    int k0 = t * 32;
    u16* sA = lds + buf * ((BM + 128) * 32);
    u16* sB = sA + BM * 32;
#pragma unroll
    for (int r = 0; r < BM / 64; ++r) {
      int ch = r * 256 + tid;
      int mm = ch >> 2, cs = ch & 3;
      glds16(A + (size_t)(m0 + mm) * K + k0 + ((cs ^ ((mm >> 1) & 3)) << 3),
             sA + ch * 8);
    }
#pragma unroll
    for (int r = 0; r < 2; ++r) {
      int ch = r * 256 + tid;
      int mm = ch >> 2, cs = ch & 3;
      glds16(Bt + (size_t)(n0 + mm) * K + k0 + ((cs ^ ((mm >> 1) & 3)) << 3),
             sB + ch * 8);
    }
  };

  stage(0, 0);
  for (int t = 0; t < 24; ++t) {
    const int cur = t & 1;
    const u16* sA = lds + cur * ((BM + 128) * 32);
    const u16* sB = sA + BM * 32;
    asm volatile("s_barrier" ::: "memory");  // all waves done with buf cur^1
    if (t < 23) {
      stage(t + 1, cur ^ 1);
      if constexpr (BM == 128)
        asm volatile("s_waitcnt vmcnt(4)" ::: "memory");
      else
        asm volatile("s_waitcnt vmcnt(3)" ::: "memory");
    } else {
      asm volatile("s_waitcnt vmcnt(0)" ::: "memory");
    }
    asm volatile("s_barrier" ::: "memory");  // all waves' tile-t data visible

    bf16x8 af[FI], bfr[4];
#pragma unroll
    for (int f = 0; f < FI; ++f) {
      int ma = wr + f * 16 + lr;
      af[f] = *(const bf16x8*)(sA + ma * 32 + ((lq ^ ((ma >> 1) & 3)) << 3));
    }
#pragma unroll
    for (int f = 0; f < 4; ++f) {
      int nb = wc + f * 16 + lr;
      bfr[f] = *(const bf16x8*)(sB + nb * 32 + ((lq ^ ((nb >> 1) & 3)) << 3));
    }
#pragma unroll
    for (int fi = 0; fi < FI; ++fi)
#pragma unroll
      for (int fj = 0; fj < 4; ++fj)
        acc[fi][fj] = __builtin_amdgcn_mfma_f32_16x16x32_bf16(
            af[fi], bfr[fj], acc[fi][fj], 0, 0, 0);
  }

#pragma unroll
  for (int fi = 0; fi < FI; ++fi) {
#pragma unroll
    for (int fj = 0; fj < 4; ++fj) {
      int row = m0 + wr + fi * 16 + lq * 4;
      int col = n0 + wc + fj * 16 + lr;
      if constexpr (PROJ) {
        float bv = bias[col];
#pragma unroll
        for (int g = 0; g < 4; ++g)
          Cf[(size_t)(row + g) * N + col] = acc[fi][fj][g] + bv;
      } else {
        if (n0 + wc >= 1536) {
          // V region: transposed into vt[bh][d][seq'] with chunk4 permutation
          // so k_attn's V-fragments are single b128 LDS reads.
          int hh = (col - 1536) >> 6, dd = col & 63;
          int sl = row & 2047;
          int g4 = (sl >> 2) & 31;
          int p = ((g4 >> 3) << 3) | ((g4 & 3) << 1) | ((g4 >> 2) & 1);
          int seqp = (sl & ~127) | (p << 2);
          u16x4 o;
#pragma unroll
          for (int g = 0; g < 4; ++g) o[g] = f2bf(acc[fi][fj][g]);
          *(u16x4*)(vt + (((size_t)(row >> 11) * 12 + hh) * 64 + dd) * 2048 +
                    seqp) = o;
        } else {
          const float qs = 0.18033688011112042f;  // 0.125*log2(e): softmax scale
          float s = (col < 768) ? qs : 1.0f;
#pragma unroll
          for (int g = 0; g < 4; ++g)
            Co[(size_t)(row + g) * N + col] = f2bf(acc[fi][fj][g] * s);
        }
      }
    }
  }
}

// ------------- flash attention: S^T form, rf=4, 48 KiB LDS (3 blocks/CU) ----------
// K double-buffered (prefetch 1 tile ahead), V single-buffered: V(t) issued at
// tile top, waited only after chunk-0 QK+exp2 (3rd barrier) so its latency hides
// behind compute while K(t+1) stays in flight across all barriers.
__global__ __launch_bounds__(256, 3) void k_attn(const u16* __restrict__ qkv,
                                                 const u16* __restrict__ vt,
                                                 u16* __restrict__ p0,
                                                 u16* __restrict__ p1,
                                                 float* __restrict__ Lp) {
  const int SEQ = 2048, C3 = 2304;
  __shared__ u16 lds[24576];  // 48 KiB: K0 @0, K1 @8192, V @16384 (u16 idx)
  const int tid = threadIdx.x;
  const int wave = tid >> 6, lane = tid & 63;
  const int lr = lane & 15, lq = lane >> 4;
  const int n0 = blockIdx.x * 256;
  const int bh = blockIdx.y;
  const int jh = blockIdx.z;
  const int b = bh / 12, h = bh % 12;
  const u16* qb = qkv + (size_t)b * SEQ * C3 + h * 64;
  const u16* kb = qb + 768;
  const u16* vb = vt + (size_t)bh * 64 * SEQ;

  // stage Q tile (256x64 = 32 KiB) across the K-dbuf region, pull B-frags to regs
#pragma unroll
  for (int r = 0; r < 8; ++r) {
    int ch = r * 256 + tid;
    int mm = ch >> 3, cs = ch & 7;
    glds16(qb + (size_t)(n0 + mm) * C3 + ((cs ^ (mm & 7)) << 3), lds + ch * 8);
  }
  __syncthreads();
  bf16x8 qf[4][2];
#pragma unroll
  for (int rf = 0; rf < 4; ++rf) {
    int mq = wave * 64 + rf * 16 + lr;
#pragma unroll
    for (int ks = 0; ks < 2; ++ks)
      qf[rf][ks] = *(const bf16x8*)(lds + (mq * 8 + ((ks * 4 + lq) ^ (mq & 7))) * 8);
  }
  __syncthreads();  // all Q reads done before buffer reuse

  const f32x4 biasC = {-8.f, -8.f, -8.f, -8.f};  // softmax bias as C operand
  union { u16x8 u; bf16x8 b; } onesU;
#pragma unroll
  for (int e = 0; e < 8; ++e) onesU.u[e] = 0x3F80;  // bf16 1.0 x8
  const bf16x8 onesA = onesU.b;
  f32x4 O[4][4] = {};
  f32x4 L5[4] = {};

  auto stageK = [&](int t, int buf) {
    int j0 = jh * 1024 + t * 128;
    u16* K_ = lds + buf * 8192;
#pragma unroll
    for (int r = 0; r < 4; ++r) {
      int ch = r * 256 + tid;
      int mm = ch >> 3, cs = ch & 7;
      glds16(kb + (size_t)(j0 + mm) * C3 + ((cs ^ (mm & 7)) << 3), K_ + ch * 8);
    }
  };
  auto stageV = [&](int t) {
    int j0 = jh * 1024 + t * 128;
    u16* V_ = lds + 16384;
#pragma unroll
    for (int r = 0; r < 4; ++r) {
      int ch = r * 256 + tid;
      int dd = ch >> 4, ct = ch & 15;
      glds16(vb + (size_t)dd * SEQ + j0 + ((ct ^ (dd & 7)) << 3), V_ + ch * 8);
    }
  };

  bf16x8 P[4];
  auto qk_chunk = [&](int c, const u16* K_) {
    f32x4 S[2][4];
#pragma unroll
    for (int j2 = 0; j2 < 2; ++j2) {
      int j = (c * 2 + j2) * 16 + lr;
      bf16x8 kf = *(const bf16x8*)(K_ + (j * 8 + (lq ^ (j & 7))) * 8);
#pragma unroll
      for (int rf = 0; rf < 4; ++rf)
        S[j2][rf] = __builtin_amdgcn_mfma_f32_16x16x32_bf16(
            kf, qf[rf][0], biasC, 0, 0, 0);
    }
#pragma unroll
    for (int j2 = 0; j2 < 2; ++j2) {
      int j = (c * 2 + j2) * 16 + lr;
      bf16x8 kf = *(const bf16x8*)(K_ + (j * 8 + ((4 + lq) ^ (j & 7))) * 8);
#pragma unroll
      for (int rf = 0; rf < 4; ++rf)
        S[j2][rf] = __builtin_amdgcn_mfma_f32_16x16x32_bf16(
            kf, qf[rf][1], S[j2][rf], 0, 0, 0);
    }
#pragma unroll
    for (int rf = 0; rf < 4; ++rf) {
      bf16x8 p8;
#pragma unroll
      for (int j2 = 0; j2 < 2; ++j2)
#pragma unroll
        for (int g = 0; g < 4; ++g)
          p8[j2 * 4 + g] = (__bf16)__builtin_amdgcn_exp2f(S[j2][rf][g]);
      P[rf] = p8;
      L5[rf] = __builtin_amdgcn_mfma_f32_16x16x32_bf16(onesA, P[rf], L5[rf],
                                                       0, 0, 0);
    }
  };
  auto pv_chunk = [&](int c, const u16* V_) {
#pragma unroll
    for (int df = 0; df < 4; ++df) {
      int d = df * 16 + lr;
      bf16x8 vf = *(const bf16x8*)(V_ + d * 128 + (((c * 4 + lq) ^ (d & 7)) << 3));
#pragma unroll
      for (int rf = 0; rf < 4; ++rf)
        O[rf][df] = __builtin_amdgcn_mfma_f32_16x16x32_bf16(
            vf, P[rf], O[rf][df], 0, 0, 0);
    }
  };

  stageK(0, 0);
  for (int t = 0; t < 8; ++t) {
    const int cur = t & 1;
    const u16* K_ = lds + cur * 8192;
    const u16* V_ = lds + 16384;
    asm volatile("s_barrier" ::: "memory");  // A: V(t-1)/K(t-1) reads all done
    stageV(t);
    if (t < 7) {
      stageK(t + 1, cur ^ 1);
      asm volatile("s_waitcnt vmcnt(8)" ::: "memory");  // drain K(t) only
    } else {
      asm volatile("s_waitcnt vmcnt(4)" ::: "memory");  // drain K(7) only
    }
    asm volatile("s_barrier" ::: "memory");  // B: K(t) visible to all waves

    qk_chunk(0, K_);
    if (t < 7)
      asm volatile("s_waitcnt vmcnt(4)" ::: "memory");  // drain V(t), keep K(t+1)
    else
      asm volatile("s_waitcnt vmcnt(0)" ::: "memory");
    asm volatile("s_barrier" ::: "memory");  // C: V(t) visible to all waves
    pv_chunk(0, V_);
#pragma unroll
    for (int c = 1; c < 4; ++c) {
      qk_chunk(c, K_);
      pv_chunk(c, V_);
    }
  }

  // epilogue: un-normalized f16 partials + per-row lsum (f32, from L5)
  u16* pd = jh ? p1 : p0;
  float* Lb = Lp + (size_t)(jh * 48 + bh) * 2048;
#pragma unroll
  for (int rf = 0; rf < 4; ++rf) {
    int rowl = n0 + wave * 64 + rf * 16 + lr;
    if (lq == 0) Lb[rowl] = L5[rf][0];  // all rows identical for ones-A
    size_t row = (size_t)b * SEQ + rowl;
#pragma unroll
    for (int df = 0; df < 4; ++df) {
      union { f16x4 h; u16x4 u; } o;
#pragma unroll
      for (int g = 0; g < 4; ++g) o.h[g] = (_Float16)O[rf][df][g];
      *(u16x4*)(pd + row * 768 + h * 64 + df * 16 + lq * 4) = o.u;
    }
  }
}

// ------------- merge split-j partials: aout = bf16((O0+O1)/(l0+l1)), in place over p1 -------
__global__ __launch_bounds__(256) void k_merge(const u16* __restrict__ p0,
                                               u16* __restrict__ p1,
                                               const float* __restrict__ Lp) {
  int t = blockIdx.x * 256 + threadIdx.x;  // 8192*192 threads, 4 ch each
  int row = t / 192, c4 = (t % 192) * 4;
  int hh = c4 >> 6;
  int bh = (row >> 11) * 12 + hh, rowl = row & 2047;
  float l = Lp[(size_t)bh * 2048 + rowl] + Lp[(size_t)(48 + bh) * 2048 + rowl];
  float inv = 1.0f / l;
  size_t off = (size_t)row * 768 + c4;
  union { f16x4 h; u16x4 u; } a, bb;
  a.u = *(const u16x4*)(p0 + off);
  bb.u = *(const u16x4*)(p1 + off);
  u16x4 o;
#pragma unroll
  for (int g = 0; g < 4; ++g)
    o[g] = f2bf(((float)a.h[g] + (float)bb.h[g]) * inv);
  *(u16x4*)(p1 + off) = o;
}

extern "C" void kernel_launch(void* const* d_in, const int* in_sizes, int n_in,
                              void* d_out, int out_size, void* d_ws, size_t ws_size,
                              hipStream_t stream) {
  const float* x = (const float*)d_in[0];
  const float* w_qkv = (const float*)d_in[1];
  const float* w_proj = (const float*)d_in[2];
  const float* b_proj = (const float*)d_in[3];
  float* out = (float*)d_out;
  char* ws = (char*)d_ws;
  u16* x_bf    = (u16*)(ws);              // [8192,768]  (recycled: attn h0 f16 partial)
  u16* wqkv_t  = (u16*)(ws + 12582912);   // [2304,768]  (recycled: lsum partials f32)
  u16* wproj_t = (u16*)(ws + 16121856);   // [768,768]
  u16* qkv     = (u16*)(ws + 17301504);   // [8192,2304] (Q,K regions only)
  u16* vt      = (u16*)(ws + 55050240);   // [48,64,2048] (chunk4-permuted)
  u16* aout    = (u16*)(ws + 67633152);   // [8192,768]  (attn h1 partial, then merged bf16)
  float* Lp    = (float*)wqkv_t;          // [2,48,2048] = 768 KiB in dead wqkv_t

  k_pre<<<3648, 256, 0, stream>>>(x, x_bf, w_qkv, wqkv_t, w_proj, wproj_t);
  k_gemm<128, 2304, false><<<dim3(64, 18), 256, 0, stream>>>(x_bf, wqkv_t, qkv,
                                                             nullptr, nullptr, vt);
  k_attn<<<dim3(8, 48, 2), 256, 0, stream>>>(qkv, vt, x_bf, aout, Lp);
  k_merge<<<6144, 256, 0, stream>>>(x_bf, aout, Lp);
  k_gemm<64, 768, true><<<dim3(128, 6), 256, 0, stream>>>(aout, wproj_t, nullptr,
                                                          out, b_proj, nullptr);
}